// Round 8
// baseline (255.410 us; speedup 1.0000x reference)
//
#include <hip/hip_runtime.h>

#define NN 1536
#define DD 512
#define PP 64
#define HH 16
#define DHD 64
#define INNER 1024
#define NCHUNK 4
#define JT_PER (NN / 64 / NCHUNK)  // 6

typedef __attribute__((ext_vector_type(4))) float f32x4;
typedef __attribute__((ext_vector_type(8))) _Float16 f16x8;
typedef __attribute__((ext_vector_type(4))) _Float16 f16x4;

__device__ inline float wave_sum(float v) {
#pragma unroll
  for (int m = 1; m <= 32; m <<= 1) v += __shfl_xor(v, m);
  return v;
}

// ---------------- merged: weight transposes + node LN ----------------
__global__ __launch_bounds__(256) void prep_kernel(const float* __restrict__ Wq,
    const float* __restrict__ Wkv, const float* __restrict__ Wg,
    const float* __restrict__ Wout, const float* __restrict__ nf,
    const float* __restrict__ lng, const float* __restrict__ lnb,
    _Float16* __restrict__ BTall, _Float16* __restrict__ WoutT,
    _Float16* __restrict__ x16) {
  int bid = blockIdx.x;
  int tid = threadIdx.x;
  if (bid >= 640) {
    // ---- node LN path ----
    int i = bid - 640;
    int c = tid * 2;
    float2 v = *(const float2*)&nf[(size_t)i * DD + c];
    float s = v.x + v.y, ss = v.x * v.x + v.y * v.y;
    s = wave_sum(s); ss = wave_sum(ss);
    __shared__ float red[2][4];
    int w = tid >> 6;
    if ((tid & 63) == 0) { red[0][w] = s; red[1][w] = ss; }
    __syncthreads();
    s = red[0][0] + red[0][1] + red[0][2] + red[0][3];
    ss = red[1][0] + red[1][1] + red[1][2] + red[1][3];
    float mean = s * (1.f / DD);
    float var = ss * (1.f / DD) - mean * mean;
    float rstd = rsqrtf(var + 1e-5f);
    x16[(size_t)i * DD + c + 0] = (_Float16)((v.x - mean) * rstd * lng[c + 0] + lnb[c + 0]);
    x16[(size_t)i * DD + c + 1] = (_Float16)((v.y - mean) * rstd * lng[c + 1] + lnb[c + 1]);
    return;
  }
  // ---- weight transpose path ----
  const float* src; int Cs, c0, r0, outStride, outCol; _Float16* dst;
  if (bid < 512) {
    int x = bid & 63, y = bid >> 6;
    int cg0 = x * 64; r0 = y * 64;
    if (cg0 < 1024)      { src = Wq;  Cs = 1024; c0 = cg0; }
    else if (cg0 < 3072) { src = Wkv; Cs = 2048; c0 = cg0 - 1024; }
    else                 { src = Wg;  Cs = 1024; c0 = cg0 - 3072; }
    dst = BTall; outStride = DD; outCol = cg0;
  } else {
    int b = bid - 512;
    int x = b & 7, y = b >> 3;
    c0 = x * 64; r0 = y * 64;
    src = Wout; Cs = DD; dst = WoutT; outStride = INNER; outCol = c0;
  }
  __shared__ float tile[64][65];
  int ri = tid >> 4, ci = (tid & 15) * 4;
#pragma unroll
  for (int p = 0; p < 4; ++p) {
    float4 v = *(const float4*)&src[(size_t)(r0 + ri + p * 16) * Cs + c0 + ci];
    tile[ri + p * 16][ci + 0] = v.x;
    tile[ri + p * 16][ci + 1] = v.y;
    tile[ri + p * 16][ci + 2] = v.z;
    tile[ri + p * 16][ci + 3] = v.w;
  }
  __syncthreads();
  int wr = tid >> 3, wc = (tid & 7) * 8;
#pragma unroll
  for (int p = 0; p < 2; ++p) {
    f16x8 o;
#pragma unroll
    for (int jj = 0; jj < 8; ++jj) o[jj] = (_Float16)tile[wc + jj][wr + p * 32];
    *(f16x8*)&dst[(size_t)(outCol + wr + p * 32) * outStride + r0 + wc] = o;
  }
}

// ---------------- f16 [R][C] -> f16 [C][R], batched over z ----------------
__global__ __launch_bounds__(256) void transpose_f16_b(const _Float16* __restrict__ in0,
    _Float16* __restrict__ out0, int R, int C) {
  const _Float16* in = in0 + (size_t)blockIdx.z * R * C;
  _Float16* out = out0 + (size_t)blockIdx.z * R * C;
  __shared__ _Float16 tile[64][72];
  int c0 = blockIdx.x * 64, r0 = blockIdx.y * 64;
  int tid = threadIdx.x;
  int ri = tid >> 3, ci = (tid & 7) * 8;
#pragma unroll
  for (int p = 0; p < 2; ++p)
    *(f16x8*)&tile[ri + p * 32][ci] = *(const f16x8*)&in[(size_t)(r0 + ri + p * 32) * C + c0 + ci];
  __syncthreads();
#pragma unroll
  for (int p = 0; p < 2; ++p) {
    f16x8 o;
#pragma unroll
    for (int jj = 0; jj < 8; ++jj) o[jj] = tile[ci + jj][ri + p * 32];
    *(f16x8*)&out[(size_t)(c0 + ri + p * 32) * R + r0 + ci] = o;
  }
}

// ---------------- fused q/kv/g projection GEMM -> prebuf16 [1536][4096] f16 ----------------
__global__ __launch_bounds__(256) void gemm_proj(const _Float16* __restrict__ A,
    const _Float16* __restrict__ BT, const float* __restrict__ bq,
    const float* __restrict__ bkv, const float* __restrict__ bg,
    _Float16* __restrict__ C) {
  __shared__ _Float16 As[64][72];
  __shared__ _Float16 Bs[64][72];
  int tid = threadIdx.x, lane = tid & 63, w = tid >> 6;
  int m0 = blockIdx.y * 64, n0 = blockIdx.x * 64;
  int wm = (w & 1) * 32, wn = (w >> 1) * 32;
  f32x4 acc[2][2] = {};
  int r = tid >> 3, c8 = (tid & 7) * 8;
  int lr = lane & 15, lg = lane >> 4;
  for (int k0 = 0; k0 < DD; k0 += 64) {
    *(f16x8*)&As[r][c8]      = *(const f16x8*)&A[(size_t)(m0 + r) * DD + k0 + c8];
    *(f16x8*)&As[r + 32][c8] = *(const f16x8*)&A[(size_t)(m0 + r + 32) * DD + k0 + c8];
    *(f16x8*)&Bs[r][c8]      = *(const f16x8*)&BT[(size_t)(n0 + r) * DD + k0 + c8];
    *(f16x8*)&Bs[r + 32][c8] = *(const f16x8*)&BT[(size_t)(n0 + r + 32) * DD + k0 + c8];
    __syncthreads();
#pragma unroll
    for (int kf = 0; kf < 2; ++kf) {
      f16x8 a0 = *(const f16x8*)&As[wm + lr][kf * 32 + lg * 8];
      f16x8 a1 = *(const f16x8*)&As[wm + 16 + lr][kf * 32 + lg * 8];
      f16x8 b0 = *(const f16x8*)&Bs[wn + lr][kf * 32 + lg * 8];
      f16x8 b1 = *(const f16x8*)&Bs[wn + 16 + lr][kf * 32 + lg * 8];
      acc[0][0] = __builtin_amdgcn_mfma_f32_16x16x32_f16(a0, b0, acc[0][0], 0, 0, 0);
      acc[0][1] = __builtin_amdgcn_mfma_f32_16x16x32_f16(a0, b1, acc[0][1], 0, 0, 0);
      acc[1][0] = __builtin_amdgcn_mfma_f32_16x16x32_f16(a1, b0, acc[1][0], 0, 0, 0);
      acc[1][1] = __builtin_amdgcn_mfma_f32_16x16x32_f16(a1, b1, acc[1][1], 0, 0, 0);
    }
    __syncthreads();
  }
#pragma unroll
  for (int mi = 0; mi < 2; ++mi)
#pragma unroll
    for (int ni = 0; ni < 2; ++ni)
#pragma unroll
      for (int rg = 0; rg < 4; ++rg) {
        int row = m0 + wm + mi * 16 + lg * 4 + rg;
        int col = n0 + wn + ni * 16 + lr;
        float bv = (col < 1024) ? bq[col] : (col < 3072) ? bkv[col - 1024] : bg[col - 3072];
        C[(size_t)row * 4096 + col] = (_Float16)(acc[mi][ni][rg] + bv);
      }
}

// ---------------- generic f16 MFMA GEMM (out proj, fp32 out) ----------------
__global__ __launch_bounds__(256) void gemm_f16(const _Float16* __restrict__ A,
    const _Float16* __restrict__ BT, const float* __restrict__ bias,
    float* __restrict__ C, int M, int N, int K) {
  __shared__ _Float16 As[64][72];
  __shared__ _Float16 Bs[64][72];
  int tid = threadIdx.x, lane = tid & 63, w = tid >> 6;
  int m0 = blockIdx.y * 64, n0 = blockIdx.x * 64;
  int wm = (w & 1) * 32, wn = (w >> 1) * 32;
  f32x4 acc[2][2] = {};
  int r = tid >> 3, c8 = (tid & 7) * 8;
  int lr = lane & 15, lg = lane >> 4;
  for (int k0 = 0; k0 < K; k0 += 64) {
    *(f16x8*)&As[r][c8]      = *(const f16x8*)&A[(size_t)(m0 + r) * K + k0 + c8];
    *(f16x8*)&As[r + 32][c8] = *(const f16x8*)&A[(size_t)(m0 + r + 32) * K + k0 + c8];
    *(f16x8*)&Bs[r][c8]      = *(const f16x8*)&BT[(size_t)(n0 + r) * K + k0 + c8];
    *(f16x8*)&Bs[r + 32][c8] = *(const f16x8*)&BT[(size_t)(n0 + r + 32) * K + k0 + c8];
    __syncthreads();
#pragma unroll
    for (int kf = 0; kf < 2; ++kf) {
      f16x8 a0 = *(const f16x8*)&As[wm + lr][kf * 32 + lg * 8];
      f16x8 a1 = *(const f16x8*)&As[wm + 16 + lr][kf * 32 + lg * 8];
      f16x8 b0 = *(const f16x8*)&Bs[wn + lr][kf * 32 + lg * 8];
      f16x8 b1 = *(const f16x8*)&Bs[wn + 16 + lr][kf * 32 + lg * 8];
      acc[0][0] = __builtin_amdgcn_mfma_f32_16x16x32_f16(a0, b0, acc[0][0], 0, 0, 0);
      acc[0][1] = __builtin_amdgcn_mfma_f32_16x16x32_f16(a0, b1, acc[0][1], 0, 0, 0);
      acc[1][0] = __builtin_amdgcn_mfma_f32_16x16x32_f16(a1, b0, acc[1][0], 0, 0, 0);
      acc[1][1] = __builtin_amdgcn_mfma_f32_16x16x32_f16(a1, b1, acc[1][1], 0, 0, 0);
    }
    __syncthreads();
  }
#pragma unroll
  for (int mi = 0; mi < 2; ++mi)
#pragma unroll
    for (int ni = 0; ni < 2; ++ni)
#pragma unroll
      for (int rg = 0; rg < 4; ++rg) {
        int row = m0 + wm + mi * 16 + lg * 4 + rg;
        int col = n0 + wn + ni * 16 + lr;
        C[(size_t)row * N + col] = acc[mi][ni][rg] + bias[col];
      }
}

// ---------------- q/k LN + head split + f16 (reads f16 prebuf) ----------------
__global__ __launch_bounds__(256) void qkv_ln_kernel(const _Float16* __restrict__ prebuf,
    const float* __restrict__ qg, const float* __restrict__ qb,
    const float* __restrict__ kg, const float* __restrict__ kb,
    _Float16* __restrict__ q16, _Float16* __restrict__ k16, _Float16* __restrict__ v16) {
  int i = blockIdx.x, tid = threadIdx.x;
  int c = tid * 4;
  const _Float16* rowp = &prebuf[(size_t)i * 4096];
  f16x4 qh = *(const f16x4*)&rowp[c];
  f16x4 kh = *(const f16x4*)&rowp[1024 + c];
  f16x4 vh = *(const f16x4*)&rowp[2048 + c];
  float qv[4], kv[4];
#pragma unroll
  for (int e = 0; e < 4; ++e) { qv[e] = (float)qh[e]; kv[e] = (float)kh[e]; }
  float qs = qv[0] + qv[1] + qv[2] + qv[3];
  float qss = qv[0] * qv[0] + qv[1] * qv[1] + qv[2] * qv[2] + qv[3] * qv[3];
  float ks = kv[0] + kv[1] + kv[2] + kv[3];
  float kss = kv[0] * kv[0] + kv[1] * kv[1] + kv[2] * kv[2] + kv[3] * kv[3];
  qs = wave_sum(qs); qss = wave_sum(qss); ks = wave_sum(ks); kss = wave_sum(kss);
  __shared__ float red[4][4];
  int w = tid >> 6;
  if ((tid & 63) == 0) { red[0][w] = qs; red[1][w] = qss; red[2][w] = ks; red[3][w] = kss; }
  __syncthreads();
  qs = red[0][0] + red[0][1] + red[0][2] + red[0][3];
  qss = red[1][0] + red[1][1] + red[1][2] + red[1][3];
  ks = red[2][0] + red[2][1] + red[2][2] + red[2][3];
  kss = red[3][0] + red[3][1] + red[3][2] + red[3][3];
  float qm = qs * (1.f / INNER), qvr = qss * (1.f / INNER) - qm * qm, qr = rsqrtf(qvr + 1e-5f);
  float km = ks * (1.f / INNER), kvr = kss * (1.f / INNER) - km * km, kr = rsqrtf(kvr + 1e-5f);
  int hh = c >> 6, d = c & 63;
  size_t off = ((size_t)hh * NN + i) * DHD + d;
  f16x4 qo, ko;
#pragma unroll
  for (int e = 0; e < 4; ++e) {
    qo[e] = (_Float16)((qv[e] - qm) * qr * qg[c + e] + qb[c + e]);
    ko[e] = (_Float16)((kv[e] - km) * kr * kg[c + e] + kb[c + e]);
  }
  *(f16x4*)&q16[off] = qo;
  *(f16x4*)&k16[off] = ko;
  *(f16x4*)&v16[off] = vh;
}

// ---------------- pair LN + Wbias einsum -> bias16 [H][N][N], i-offset ----------------
__global__ __launch_bounds__(256) void pair_bias_kernel(const float* __restrict__ pair,
    const float* __restrict__ pg, const float* __restrict__ pb,
    const float* __restrict__ Wbias, _Float16* __restrict__ bias16, int i0) {
  int i = i0 + blockIdx.x;
  int tid = threadIdx.x, lane = tid & 63, w = tid >> 6;
  int lj = lane & 15, pbase = (lane >> 4) * 8;
  f16x8 wb0, wb1;
#pragma unroll
  for (int jj = 0; jj < 8; ++jj) {
    wb0[jj] = (_Float16)Wbias[(pbase + jj) * HH + lj];
    wb1[jj] = (_Float16)Wbias[(pbase + 32 + jj) * HH + lj];
  }
  float4 g0 = *(const float4*)&pg[pbase],      g1 = *(const float4*)&pg[pbase + 4];
  float4 g2 = *(const float4*)&pg[pbase + 32], g3 = *(const float4*)&pg[pbase + 36];
  float4 b0 = *(const float4*)&pb[pbase],      b1 = *(const float4*)&pb[pbase + 4];
  float4 b2 = *(const float4*)&pb[pbase + 32], b3 = *(const float4*)&pb[pbase + 36];
  __shared__ _Float16 trans[2][16][72];
  int jbase = blockIdx.y * 256 + w * 16 + lj;
  const float* src = &pair[((size_t)i * NN + jbase) * PP];
  float4 v0 = *(const float4*)&src[pbase];
  float4 v1 = *(const float4*)&src[pbase + 4];
  float4 v2 = *(const float4*)&src[pbase + 32];
  float4 v3 = *(const float4*)&src[pbase + 36];
  for (int t4 = 0; t4 < 4; ++t4) {
    int jt0 = blockIdx.y * 256 + t4 * 64;
    float4 n0, n1, n2, n3;
    if (t4 < 3) {
      const float* nsrc = &pair[((size_t)i * NN + jbase + (t4 + 1) * 64) * PP];
      n0 = *(const float4*)&nsrc[pbase];
      n1 = *(const float4*)&nsrc[pbase + 4];
      n2 = *(const float4*)&nsrc[pbase + 32];
      n3 = *(const float4*)&nsrc[pbase + 36];
    }
    float s = v0.x + v0.y + v0.z + v0.w + v1.x + v1.y + v1.z + v1.w
            + v2.x + v2.y + v2.z + v2.w + v3.x + v3.y + v3.z + v3.w;
    float ss = v0.x * v0.x + v0.y * v0.y + v0.z * v0.z + v0.w * v0.w
             + v1.x * v1.x + v1.y * v1.y + v1.z * v1.z + v1.w * v1.w
             + v2.x * v2.x + v2.y * v2.y + v2.z * v2.z + v2.w * v2.w
             + v3.x * v3.x + v3.y * v3.y + v3.z * v3.z + v3.w * v3.w;
    s += __shfl_xor(s, 16); s += __shfl_xor(s, 32);
    ss += __shfl_xor(ss, 16); ss += __shfl_xor(ss, 32);
    float mean = s * (1.f / PP);
    float var = ss * (1.f / PP) - mean * mean;
    float rstd = rsqrtf(var + 1e-5f);
    f16x8 a0, a1;
    a0[0] = (_Float16)((v0.x - mean) * rstd * g0.x + b0.x);
    a0[1] = (_Float16)((v0.y - mean) * rstd * g0.y + b0.y);
    a0[2] = (_Float16)((v0.z - mean) * rstd * g0.z + b0.z);
    a0[3] = (_Float16)((v0.w - mean) * rstd * g0.w + b0.w);
    a0[4] = (_Float16)((v1.x - mean) * rstd * g1.x + b1.x);
    a0[5] = (_Float16)((v1.y - mean) * rstd * g1.y + b1.y);
    a0[6] = (_Float16)((v1.z - mean) * rstd * g1.z + b1.z);
    a0[7] = (_Float16)((v1.w - mean) * rstd * g1.w + b1.w);
    a1[0] = (_Float16)((v2.x - mean) * rstd * g2.x + b2.x);
    a1[1] = (_Float16)((v2.y - mean) * rstd * g2.y + b2.y);
    a1[2] = (_Float16)((v2.z - mean) * rstd * g2.z + b2.z);
    a1[3] = (_Float16)((v2.w - mean) * rstd * g2.w + b2.w);
    a1[4] = (_Float16)((v3.x - mean) * rstd * g3.x + b3.x);
    a1[5] = (_Float16)((v3.y - mean) * rstd * g3.y + b3.y);
    a1[6] = (_Float16)((v3.z - mean) * rstd * g3.z + b3.z);
    a1[7] = (_Float16)((v3.w - mean) * rstd * g3.w + b3.w);
    f32x4 cacc = {};
    cacc = __builtin_amdgcn_mfma_f32_16x16x32_f16(a0, wb0, cacc, 0, 0, 0);
    cacc = __builtin_amdgcn_mfma_f32_16x16x32_f16(a1, wb1, cacc, 0, 0, 0);
#pragma unroll
    for (int rg = 0; rg < 4; ++rg)
      trans[t4 & 1][lj][w * 16 + (lane >> 4) * 4 + rg] = (_Float16)cacc[rg];
    __syncthreads();
    int hh = tid >> 4, jc = (tid & 15) * 4;
    f16x4 ov = *(const f16x4*)&trans[t4 & 1][hh][jc];
    *(f16x4*)&bias16[((size_t)hh * NN + i) * NN + jt0 + jc] = ov;
    v0 = n0; v1 = n1; v2 = n2; v3 = n3;
  }
}

// ---------------- flash attention (it-offset): LDS K/V reg-prefetch, direct bias ----------------
__global__ __launch_bounds__(256) void attn_kernel(const _Float16* __restrict__ q16,
    const _Float16* __restrict__ k16, const _Float16* __restrict__ vT16,
    const _Float16* __restrict__ bias16, _Float16* __restrict__ opart,
    float* __restrict__ mlbuf, int it0) {
  int it = it0 + blockIdx.x, h = blockIdx.y, ck = blockIdx.z;
  int tid = threadIdx.x, lane = tid & 63, w = tid >> 6;
  int lr = lane & 15, lg = lane >> 4;
  __shared__ _Float16 Kt[64][72];
  __shared__ _Float16 Vt[64][72];
  int ib0 = it * 64;
  int ib = ib0 + w * 16;
  f16x8 qb0 = *(const f16x8*)&q16[((size_t)h * NN + ib + lr) * DHD + lg * 8];
  f16x8 qb1 = *(const f16x8*)&q16[((size_t)h * NN + ib + lr) * DHD + 32 + lg * 8];
  float m = -INFINITY, lsum = 0.f;
  f32x4 oacc[4] = {};
  int sr = tid >> 3, sc = (tid & 7) * 8;
  int jt0g = ck * JT_PER;
  const _Float16* brow = &bias16[((size_t)h * NN + ib + lr) * NN];
  f16x8 kA, kB, vA, vB;
  {
    int j0 = jt0g * 64;
    kA = *(const f16x8*)&k16[((size_t)h * NN + j0 + sr) * DHD + sc];
    kB = *(const f16x8*)&k16[((size_t)h * NN + j0 + sr + 32) * DHD + sc];
    vA = *(const f16x8*)&vT16[((size_t)h * DHD + sr) * NN + j0 + sc];
    vB = *(const f16x8*)&vT16[((size_t)h * DHD + sr + 32) * NN + j0 + sc];
  }
  for (int jj = 0; jj < JT_PER; ++jj) {
    int j0 = (jt0g + jj) * 64;
    *(f16x8*)&Kt[sr][sc] = kA;
    *(f16x8*)&Kt[sr + 32][sc] = kB;
    *(f16x8*)&Vt[sr][sc] = vA;
    *(f16x8*)&Vt[sr + 32][sc] = vB;
    f16x4 bl[4];
#pragma unroll
    for (int jq = 0; jq < 4; ++jq)
      bl[jq] = *(const f16x4*)&brow[j0 + jq * 16 + lg * 4];
    __syncthreads();
    if (jj + 1 < JT_PER) {
      int j1 = j0 + 64;
      kA = *(const f16x8*)&k16[((size_t)h * NN + j1 + sr) * DHD + sc];
      kB = *(const f16x8*)&k16[((size_t)h * NN + j1 + sr + 32) * DHD + sc];
      vA = *(const f16x8*)&vT16[((size_t)h * DHD + sr) * NN + j1 + sc];
      vB = *(const f16x8*)&vT16[((size_t)h * DHD + sr + 32) * NN + j1 + sc];
    }
    float s[4][4];
#pragma unroll
    for (int jq = 0; jq < 4; ++jq) {
      f16x8 ka0 = *(const f16x8*)&Kt[jq * 16 + lr][lg * 8];
      f16x8 ka1 = *(const f16x8*)&Kt[jq * 16 + lr][32 + lg * 8];
      f32x4 c = {};
      c = __builtin_amdgcn_mfma_f32_16x16x32_f16(ka0, qb0, c, 0, 0, 0);
      c = __builtin_amdgcn_mfma_f32_16x16x32_f16(ka1, qb1, c, 0, 0, 0);
#pragma unroll
      for (int r = 0; r < 4; ++r)
        s[jq][r] = c[r] * 0.125f + (float)bl[jq][r];
    }
    float tmax = s[0][0];
#pragma unroll
    for (int jq = 0; jq < 4; ++jq)
#pragma unroll
      for (int r = 0; r < 4; ++r) tmax = fmaxf(tmax, s[jq][r]);
    tmax = fmaxf(tmax, __shfl_xor(tmax, 16));
    tmax = fmaxf(tmax, __shfl_xor(tmax, 32));
    float mn = fmaxf(m, tmax);
    float alpha = __expf(m - mn);
    float ps = 0.f;
    f16x4 pf[4];
#pragma unroll
    for (int jq = 0; jq < 4; ++jq)
#pragma unroll
      for (int r = 0; r < 4; ++r) {
        float p = __expf(s[jq][r] - mn);
        ps += p;
        pf[jq][r] = (_Float16)p;
      }
    ps += __shfl_xor(ps, 16);
    ps += __shfl_xor(ps, 32);
    lsum = lsum * alpha + ps;
    m = mn;
    float ar[4];
#pragma unroll
    for (int r = 0; r < 4; ++r) ar[r] = __shfl(alpha, lg * 4 + r);
#pragma unroll
    for (int dt = 0; dt < 4; ++dt)
#pragma unroll
      for (int r = 0; r < 4; ++r) oacc[dt][r] *= ar[r];
#pragma unroll
    for (int dt = 0; dt < 4; ++dt)
#pragma unroll
      for (int jq = 0; jq < 4; ++jq) {
        f16x4 vb = *(const f16x4*)&Vt[dt * 16 + lr][jq * 16 + lg * 4];
        oacc[dt] = __builtin_amdgcn_mfma_f32_16x16x16f16(pf[jq], vb, oacc[dt], 0, 0, 0);
      }
    __syncthreads();
  }
  size_t pbase = (((size_t)it * HH + h) * NCHUNK + ck) * 4096 + (size_t)w * 1024;
#pragma unroll
  for (int dt = 0; dt < 4; ++dt) {
    f16x4 ov;
#pragma unroll
    for (int r = 0; r < 4; ++r) ov[r] = (_Float16)oacc[dt][r];
    *(f16x4*)&opart[pbase + dt * 256 + lane * 4] = ov;
  }
  if (lg == 0) {
    size_t mb = (((size_t)it * HH + h) * NCHUNK + ck) * 128;
    mlbuf[mb + w * 16 + lr] = m;
    mlbuf[mb + 64 + w * 16 + lr] = lsum;
  }
}

// ---------------- flash merge + gating -> o16 ----------------
__global__ __launch_bounds__(256) void attn_merge(const _Float16* __restrict__ opart,
    const float* __restrict__ mlbuf, const _Float16* __restrict__ prebuf,
    _Float16* __restrict__ o16) {
  int it = blockIdx.x, h = blockIdx.y;
  int tid = threadIdx.x, lane = tid & 63, w = tid >> 6;
  int lr = lane & 15, lg = lane >> 4;
  __shared__ float sm[NCHUNK][64], sl[NCHUNK][64];
  {
    int c = tid >> 6, i = tid & 63;
    size_t mb = (((size_t)it * HH + h) * NCHUNK + c) * 128;
    sm[c][i] = mlbuf[mb + i];
    sl[c][i] = mlbuf[mb + 64 + i];
  }
  __syncthreads();
  float wc[NCHUNK][4], linv[4];
#pragma unroll
  for (int r = 0; r < 4; ++r) {
    int i_loc = w * 16 + lg * 4 + r;
    float mg = sm[0][i_loc];
#pragma unroll
    for (int c = 1; c < NCHUNK; ++c) mg = fmaxf(mg, sm[c][i_loc]);
    float lt = 0.f;
#pragma unroll
    for (int c = 0; c < NCHUNK; ++c) {
      float e = __expf(sm[c][i_loc] - mg);
      wc[c][r] = e;
      lt += e * sl[c][i_loc];
    }
    linv[r] = 1.f / lt;
  }
  size_t base = ((size_t)it * HH + h) * NCHUNK * 4096 + (size_t)w * 1024;
#pragma unroll
  for (int dt = 0; dt < 4; ++dt) {
    float o[4] = {};
#pragma unroll
    for (int c = 0; c < NCHUNK; ++c) {
      f16x4 v = *(const f16x4*)&opart[base + (size_t)c * 4096 + dt * 256 + lane * 4];
#pragma unroll
      for (int r = 0; r < 4; ++r) o[r] += wc[c][r] * (float)v[r];
    }
    int d = dt * 16 + lr;
#pragma unroll
    for (int r = 0; r < 4; ++r) {
      int i = it * 64 + w * 16 + lg * 4 + r;
      float gt = (float)prebuf[(size_t)i * 4096 + 3072 + h * DHD + d];
      float val = o[r] * linv[r] * (1.f / (1.f + __expf(-gt)));
      o16[(size_t)i * INNER + h * DHD + d] = (_Float16)val;
    }
  }
}

extern "C" void kernel_launch(void* const* d_in, const int* in_sizes, int n_in,
                              void* d_out, int out_size, void* d_ws, size_t ws_size,
                              hipStream_t stream) {
  const float* node  = (const float*)d_in[0];
  const float* pair  = (const float*)d_in[1];
  const float* ln_ng = (const float*)d_in[3];
  const float* ln_nb = (const float*)d_in[4];
  const float* ln_pg = (const float*)d_in[5];
  const float* ln_pb = (const float*)d_in[6];
  const float* Wq    = (const float*)d_in[7];
  const float* bq    = (const float*)d_in[8];
  const float* Wkv   = (const float*)d_in[9];
  const float* bkv   = (const float*)d_in[10];
  const float* qlg   = (const float*)d_in[11];
  const float* qlb   = (const float*)d_in[12];
  const float* klg   = (const float*)d_in[13];
  const float* klb   = (const float*)d_in[14];
  const float* Wg    = (const float*)d_in[15];
  const float* bg    = (const float*)d_in[16];
  const float* Wbias = (const float*)d_in[17];
  const float* Wout  = (const float*)d_in[18];
  const float* bout  = (const float*)d_in[19];
  float* out = (float*)d_out;

  char* ws = (char*)d_ws;
  const size_t MB = 1u << 20;
  _Float16* BTall    = (_Float16*)(ws + 0 * MB);
  _Float16* WoutT    = (_Float16*)(ws + 4 * MB);
  _Float16* x16      = (_Float16*)(ws + 5 * MB);
  _Float16* prebuf16 = (_Float16*)(ws + 8 * MB);
  _Float16* q16      = (_Float16*)(ws + 20 * MB);
  _Float16* k16      = (_Float16*)(ws + 23 * MB);
  _Float16* v16      = (_Float16*)(ws + 26 * MB);
  _Float16* vT16     = (_Float16*)(ws + 29 * MB);
  _Float16* o16      = (_Float16*)(ws + 32 * MB);
  _Float16* bias16   = (_Float16*)(ws + 36 * MB);
  _Float16* opart    = (_Float16*)(ws + 112 * MB);
  float*    mlbuf    = (float*)(ws + 126 * MB);

  prep_kernel<<<640 + NN, 256, 0, stream>>>(Wq, Wkv, Wg, Wout, node, ln_ng, ln_nb,
                                            BTall, WoutT, x16);
  gemm_proj<<<dim3(4096 / 64, NN / 64), 256, 0, stream>>>(x16, BTall, bq, bkv, bg, prebuf16);
  qkv_ln_kernel<<<NN, 256, 0, stream>>>(prebuf16, qlg, qlb, klg, klb, q16, k16, v16);
  transpose_f16_b<<<dim3(1, NN / 64, HH), 256, 0, stream>>>(v16, vT16, NN, DHD);

  // interleaved i-halves: bias16 half stays L3-resident for its attention pass
  pair_bias_kernel<<<dim3(NN / 2, NN / 256), 256, 0, stream>>>(pair, ln_pg, ln_pb, Wbias, bias16, 0);
  attn_kernel<<<dim3(NN / 128, HH, NCHUNK), 256, 0, stream>>>(q16, k16, vT16, bias16, opart, mlbuf, 0);
  pair_bias_kernel<<<dim3(NN / 2, NN / 256), 256, 0, stream>>>(pair, ln_pg, ln_pb, Wbias, bias16, NN / 2);
  attn_kernel<<<dim3(NN / 128, HH, NCHUNK), 256, 0, stream>>>(q16, k16, vT16, bias16, opart, mlbuf, NN / 128);

  attn_merge<<<dim3(NN / 64, HH), 256, 0, stream>>>(opart, mlbuf, prebuf16, o16);
  gemm_f16<<<dim3(DD / 64, NN / 64), 256, 0, stream>>>(o16, WoutT, bout, out, NN, DD, INNER);
}

// Round 9
// 239.526 us; speedup vs baseline: 1.0663x; 1.0663x over previous
//
#include <hip/hip_runtime.h>

#define NN 1536
#define DD 512
#define PP 64
#define HH 16
#define DHD 64
#define INNER 1024
#define NCHUNK 4
#define JT_PER (NN / 64 / NCHUNK)  // 6

typedef __attribute__((ext_vector_type(4))) float f32x4;
typedef __attribute__((ext_vector_type(8))) _Float16 f16x8;
typedef __attribute__((ext_vector_type(4))) _Float16 f16x4;

__device__ inline float wave_sum(float v) {
#pragma unroll
  for (int m = 1; m <= 32; m <<= 1) v += __shfl_xor(v, m);
  return v;
}

// ---------------- merged: weight transposes + node LN ----------------
__global__ __launch_bounds__(256) void prep_kernel(const float* __restrict__ Wq,
    const float* __restrict__ Wkv, const float* __restrict__ Wg,
    const float* __restrict__ Wout, const float* __restrict__ nf,
    const float* __restrict__ lng, const float* __restrict__ lnb,
    _Float16* __restrict__ BTall, _Float16* __restrict__ WoutT,
    _Float16* __restrict__ x16) {
  int bid = blockIdx.x;
  int tid = threadIdx.x;
  if (bid >= 640) {
    int i = bid - 640;
    int c = tid * 2;
    float2 v = *(const float2*)&nf[(size_t)i * DD + c];
    float s = v.x + v.y, ss = v.x * v.x + v.y * v.y;
    s = wave_sum(s); ss = wave_sum(ss);
    __shared__ float red[2][4];
    int w = tid >> 6;
    if ((tid & 63) == 0) { red[0][w] = s; red[1][w] = ss; }
    __syncthreads();
    s = red[0][0] + red[0][1] + red[0][2] + red[0][3];
    ss = red[1][0] + red[1][1] + red[1][2] + red[1][3];
    float mean = s * (1.f / DD);
    float var = ss * (1.f / DD) - mean * mean;
    float rstd = rsqrtf(var + 1e-5f);
    x16[(size_t)i * DD + c + 0] = (_Float16)((v.x - mean) * rstd * lng[c + 0] + lnb[c + 0]);
    x16[(size_t)i * DD + c + 1] = (_Float16)((v.y - mean) * rstd * lng[c + 1] + lnb[c + 1]);
    return;
  }
  const float* src; int Cs, c0, r0, outStride, outCol; _Float16* dst;
  if (bid < 512) {
    int x = bid & 63, y = bid >> 6;
    int cg0 = x * 64; r0 = y * 64;
    if (cg0 < 1024)      { src = Wq;  Cs = 1024; c0 = cg0; }
    else if (cg0 < 3072) { src = Wkv; Cs = 2048; c0 = cg0 - 1024; }
    else                 { src = Wg;  Cs = 1024; c0 = cg0 - 3072; }
    dst = BTall; outStride = DD; outCol = cg0;
  } else {
    int b = bid - 512;
    int x = b & 7, y = b >> 3;
    c0 = x * 64; r0 = y * 64;
    src = Wout; Cs = DD; dst = WoutT; outStride = INNER; outCol = c0;
  }
  __shared__ float tile[64][65];
  int ri = tid >> 4, ci = (tid & 15) * 4;
#pragma unroll
  for (int p = 0; p < 4; ++p) {
    float4 v = *(const float4*)&src[(size_t)(r0 + ri + p * 16) * Cs + c0 + ci];
    tile[ri + p * 16][ci + 0] = v.x;
    tile[ri + p * 16][ci + 1] = v.y;
    tile[ri + p * 16][ci + 2] = v.z;
    tile[ri + p * 16][ci + 3] = v.w;
  }
  __syncthreads();
  int wr = tid >> 3, wc = (tid & 7) * 8;
#pragma unroll
  for (int p = 0; p < 2; ++p) {
    f16x8 o;
#pragma unroll
    for (int jj = 0; jj < 8; ++jj) o[jj] = (_Float16)tile[wc + jj][wr + p * 32];
    *(f16x8*)&dst[(size_t)(outCol + wr + p * 32) * outStride + r0 + wc] = o;
  }
}

// ---------------- PB body (device) ----------------
__device__ __forceinline__ void pb_body(int i, int jy, int tid,
    const float* __restrict__ pair, const float* __restrict__ pg,
    const float* __restrict__ pb, const float* __restrict__ Wbias,
    _Float16* __restrict__ bias16) {
  int lane = tid & 63, w = tid >> 6;
  int lj = lane & 15, pbase = (lane >> 4) * 8;
  f16x8 wb0, wb1;
#pragma unroll
  for (int jj = 0; jj < 8; ++jj) {
    wb0[jj] = (_Float16)Wbias[(pbase + jj) * HH + lj];
    wb1[jj] = (_Float16)Wbias[(pbase + 32 + jj) * HH + lj];
  }
  float4 g0 = *(const float4*)&pg[pbase],      g1 = *(const float4*)&pg[pbase + 4];
  float4 g2 = *(const float4*)&pg[pbase + 32], g3 = *(const float4*)&pg[pbase + 36];
  float4 b0 = *(const float4*)&pb[pbase],      b1 = *(const float4*)&pb[pbase + 4];
  float4 b2 = *(const float4*)&pb[pbase + 32], b3 = *(const float4*)&pb[pbase + 36];
  __shared__ _Float16 trans[2][16][72];
  int jbase = jy * 256 + w * 16 + lj;
  const float* src = &pair[((size_t)i * NN + jbase) * PP];
  float4 v0 = *(const float4*)&src[pbase];
  float4 v1 = *(const float4*)&src[pbase + 4];
  float4 v2 = *(const float4*)&src[pbase + 32];
  float4 v3 = *(const float4*)&src[pbase + 36];
  for (int t4 = 0; t4 < 4; ++t4) {
    int jt0 = jy * 256 + t4 * 64;
    float4 n0, n1, n2, n3;
    if (t4 < 3) {
      const float* nsrc = &pair[((size_t)i * NN + jbase + (t4 + 1) * 64) * PP];
      n0 = *(const float4*)&nsrc[pbase];
      n1 = *(const float4*)&nsrc[pbase + 4];
      n2 = *(const float4*)&nsrc[pbase + 32];
      n3 = *(const float4*)&nsrc[pbase + 36];
    }
    float s = v0.x + v0.y + v0.z + v0.w + v1.x + v1.y + v1.z + v1.w
            + v2.x + v2.y + v2.z + v2.w + v3.x + v3.y + v3.z + v3.w;
    float ss = v0.x * v0.x + v0.y * v0.y + v0.z * v0.z + v0.w * v0.w
             + v1.x * v1.x + v1.y * v1.y + v1.z * v1.z + v1.w * v1.w
             + v2.x * v2.x + v2.y * v2.y + v2.z * v2.z + v2.w * v2.w
             + v3.x * v3.x + v3.y * v3.y + v3.z * v3.z + v3.w * v3.w;
    s += __shfl_xor(s, 16); s += __shfl_xor(s, 32);
    ss += __shfl_xor(ss, 16); ss += __shfl_xor(ss, 32);
    float mean = s * (1.f / PP);
    float var = ss * (1.f / PP) - mean * mean;
    float rstd = rsqrtf(var + 1e-5f);
    f16x8 a0, a1;
    a0[0] = (_Float16)((v0.x - mean) * rstd * g0.x + b0.x);
    a0[1] = (_Float16)((v0.y - mean) * rstd * g0.y + b0.y);
    a0[2] = (_Float16)((v0.z - mean) * rstd * g0.z + b0.z);
    a0[3] = (_Float16)((v0.w - mean) * rstd * g0.w + b0.w);
    a0[4] = (_Float16)((v1.x - mean) * rstd * g1.x + b1.x);
    a0[5] = (_Float16)((v1.y - mean) * rstd * g1.y + b1.y);
    a0[6] = (_Float16)((v1.z - mean) * rstd * g1.z + b1.z);
    a0[7] = (_Float16)((v1.w - mean) * rstd * g1.w + b1.w);
    a1[0] = (_Float16)((v2.x - mean) * rstd * g2.x + b2.x);
    a1[1] = (_Float16)((v2.y - mean) * rstd * g2.y + b2.y);
    a1[2] = (_Float16)((v2.z - mean) * rstd * g2.z + b2.z);
    a1[3] = (_Float16)((v2.w - mean) * rstd * g2.w + b2.w);
    a1[4] = (_Float16)((v3.x - mean) * rstd * g3.x + b3.x);
    a1[5] = (_Float16)((v3.y - mean) * rstd * g3.y + b3.y);
    a1[6] = (_Float16)((v3.z - mean) * rstd * g3.z + b3.z);
    a1[7] = (_Float16)((v3.w - mean) * rstd * g3.w + b3.w);
    f32x4 cacc = {};
    cacc = __builtin_amdgcn_mfma_f32_16x16x32_f16(a0, wb0, cacc, 0, 0, 0);
    cacc = __builtin_amdgcn_mfma_f32_16x16x32_f16(a1, wb1, cacc, 0, 0, 0);
#pragma unroll
    for (int rg = 0; rg < 4; ++rg)
      trans[t4 & 1][lj][w * 16 + (lane >> 4) * 4 + rg] = (_Float16)cacc[rg];
    __syncthreads();
    int hh = tid >> 4, jc = (tid & 15) * 4;
    f16x4 ov = *(const f16x4*)&trans[t4 & 1][hh][jc];
    *(f16x4*)&bias16[((size_t)hh * NN + i) * NN + jt0 + jc] = ov;
    v0 = n0; v1 = n1; v2 = n2; v3 = n3;
  }
}

// ---------------- gemm_proj body (device) ----------------
__device__ __forceinline__ void gemm_proj_body(int m0, int n0, int tid,
    const _Float16* __restrict__ A, const _Float16* __restrict__ BT,
    const float* __restrict__ bq, const float* __restrict__ bkv,
    const float* __restrict__ bg, _Float16* __restrict__ C) {
  __shared__ _Float16 As[64][72];
  __shared__ _Float16 Bs[64][72];
  int lane = tid & 63, w = tid >> 6;
  int wm = (w & 1) * 32, wn = (w >> 1) * 32;
  f32x4 acc[2][2] = {};
  int r = tid >> 3, c8 = (tid & 7) * 8;
  int lr = lane & 15, lg = lane >> 4;
  for (int k0 = 0; k0 < DD; k0 += 64) {
    *(f16x8*)&As[r][c8]      = *(const f16x8*)&A[(size_t)(m0 + r) * DD + k0 + c8];
    *(f16x8*)&As[r + 32][c8] = *(const f16x8*)&A[(size_t)(m0 + r + 32) * DD + k0 + c8];
    *(f16x8*)&Bs[r][c8]      = *(const f16x8*)&BT[(size_t)(n0 + r) * DD + k0 + c8];
    *(f16x8*)&Bs[r + 32][c8] = *(const f16x8*)&BT[(size_t)(n0 + r + 32) * DD + k0 + c8];
    __syncthreads();
#pragma unroll
    for (int kf = 0; kf < 2; ++kf) {
      f16x8 a0 = *(const f16x8*)&As[wm + lr][kf * 32 + lg * 8];
      f16x8 a1 = *(const f16x8*)&As[wm + 16 + lr][kf * 32 + lg * 8];
      f16x8 b0 = *(const f16x8*)&Bs[wn + lr][kf * 32 + lg * 8];
      f16x8 b1 = *(const f16x8*)&Bs[wn + 16 + lr][kf * 32 + lg * 8];
      acc[0][0] = __builtin_amdgcn_mfma_f32_16x16x32_f16(a0, b0, acc[0][0], 0, 0, 0);
      acc[0][1] = __builtin_amdgcn_mfma_f32_16x16x32_f16(a0, b1, acc[0][1], 0, 0, 0);
      acc[1][0] = __builtin_amdgcn_mfma_f32_16x16x32_f16(a1, b0, acc[1][0], 0, 0, 0);
      acc[1][1] = __builtin_amdgcn_mfma_f32_16x16x32_f16(a1, b1, acc[1][1], 0, 0, 0);
    }
    __syncthreads();
  }
#pragma unroll
  for (int mi = 0; mi < 2; ++mi)
#pragma unroll
    for (int ni = 0; ni < 2; ++ni)
#pragma unroll
      for (int rg = 0; rg < 4; ++rg) {
        int row = m0 + wm + mi * 16 + lg * 4 + rg;
        int col = n0 + wn + ni * 16 + lr;
        float bv = (col < 1024) ? bq[col] : (col < 3072) ? bkv[col - 1024] : bg[col - 3072];
        C[(size_t)row * 4096 + col] = (_Float16)(acc[mi][ni][rg] + bv);
      }
}

// ---------------- FAT: pair_bias (9216 blocks) interleaved 6:1 with gemm_proj (1536) ----------------
__global__ __launch_bounds__(256) void fat_pb_gemm(const float* __restrict__ pair,
    const float* __restrict__ pg, const float* __restrict__ pb,
    const float* __restrict__ Wbias, _Float16* __restrict__ bias16,
    const _Float16* __restrict__ x16, const _Float16* __restrict__ BTall,
    const float* __restrict__ bq, const float* __restrict__ bkv,
    const float* __restrict__ bg, _Float16* __restrict__ prebuf16) {
  int bid = blockIdx.x;
  int g = bid / 7, r = bid - g * 7;
  int tid = threadIdx.x;
  if (r == 6) {
    // gemm block g in [0,1536): n-block = g & 63, m-block = g >> 6
    gemm_proj_body((g >> 6) * 64, (g & 63) * 64, tid, x16, BTall, bq, bkv, bg, prebuf16);
  } else {
    int p = g * 6 + r;          // [0, 9216)
    int jy = p / NN;            // [0, 6)
    int i = p - jy * NN;        // [0, 1536)
    pb_body(i, jy, tid, pair, pg, pb, Wbias, bias16);
  }
}

// ---------------- f16 [R][C] -> f16 [C][R], batched over z ----------------
__global__ __launch_bounds__(256) void transpose_f16_b(const _Float16* __restrict__ in0,
    _Float16* __restrict__ out0, int R, int C) {
  const _Float16* in = in0 + (size_t)blockIdx.z * R * C;
  _Float16* out = out0 + (size_t)blockIdx.z * R * C;
  __shared__ _Float16 tile[64][72];
  int c0 = blockIdx.x * 64, r0 = blockIdx.y * 64;
  int tid = threadIdx.x;
  int ri = tid >> 3, ci = (tid & 7) * 8;
#pragma unroll
  for (int p = 0; p < 2; ++p)
    *(f16x8*)&tile[ri + p * 32][ci] = *(const f16x8*)&in[(size_t)(r0 + ri + p * 32) * C + c0 + ci];
  __syncthreads();
#pragma unroll
  for (int p = 0; p < 2; ++p) {
    f16x8 o;
#pragma unroll
    for (int jj = 0; jj < 8; ++jj) o[jj] = tile[ci + jj][ri + p * 32];
    *(f16x8*)&out[(size_t)(c0 + ri + p * 32) * R + r0 + ci] = o;
  }
}

// ---------------- generic f16 MFMA GEMM (out proj, fp32 out) ----------------
__global__ __launch_bounds__(256) void gemm_f16(const _Float16* __restrict__ A,
    const _Float16* __restrict__ BT, const float* __restrict__ bias,
    float* __restrict__ C, int M, int N, int K) {
  __shared__ _Float16 As[64][72];
  __shared__ _Float16 Bs[64][72];
  int tid = threadIdx.x, lane = tid & 63, w = tid >> 6;
  int m0 = blockIdx.y * 64, n0 = blockIdx.x * 64;
  int wm = (w & 1) * 32, wn = (w >> 1) * 32;
  f32x4 acc[2][2] = {};
  int r = tid >> 3, c8 = (tid & 7) * 8;
  int lr = lane & 15, lg = lane >> 4;
  for (int k0 = 0; k0 < K; k0 += 64) {
    *(f16x8*)&As[r][c8]      = *(const f16x8*)&A[(size_t)(m0 + r) * K + k0 + c8];
    *(f16x8*)&As[r + 32][c8] = *(const f16x8*)&A[(size_t)(m0 + r + 32) * K + k0 + c8];
    *(f16x8*)&Bs[r][c8]      = *(const f16x8*)&BT[(size_t)(n0 + r) * K + k0 + c8];
    *(f16x8*)&Bs[r + 32][c8] = *(const f16x8*)&BT[(size_t)(n0 + r + 32) * K + k0 + c8];
    __syncthreads();
#pragma unroll
    for (int kf = 0; kf < 2; ++kf) {
      f16x8 a0 = *(const f16x8*)&As[wm + lr][kf * 32 + lg * 8];
      f16x8 a1 = *(const f16x8*)&As[wm + 16 + lr][kf * 32 + lg * 8];
      f16x8 b0 = *(const f16x8*)&Bs[wn + lr][kf * 32 + lg * 8];
      f16x8 b1 = *(const f16x8*)&Bs[wn + 16 + lr][kf * 32 + lg * 8];
      acc[0][0] = __builtin_amdgcn_mfma_f32_16x16x32_f16(a0, b0, acc[0][0], 0, 0, 0);
      acc[0][1] = __builtin_amdgcn_mfma_f32_16x16x32_f16(a0, b1, acc[0][1], 0, 0, 0);
      acc[1][0] = __builtin_amdgcn_mfma_f32_16x16x32_f16(a1, b0, acc[1][0], 0, 0, 0);
      acc[1][1] = __builtin_amdgcn_mfma_f32_16x16x32_f16(a1, b1, acc[1][1], 0, 0, 0);
    }
    __syncthreads();
  }
#pragma unroll
  for (int mi = 0; mi < 2; ++mi)
#pragma unroll
    for (int ni = 0; ni < 2; ++ni)
#pragma unroll
      for (int rg = 0; rg < 4; ++rg) {
        int row = m0 + wm + mi * 16 + lg * 4 + rg;
        int col = n0 + wn + ni * 16 + lr;
        C[(size_t)row * N + col] = acc[mi][ni][rg] + bias[col];
      }
}

// ---------------- q/k LN + head split + f16 (reads f16 prebuf) ----------------
__global__ __launch_bounds__(256) void qkv_ln_kernel(const _Float16* __restrict__ prebuf,
    const float* __restrict__ qg, const float* __restrict__ qb,
    const float* __restrict__ kg, const float* __restrict__ kb,
    _Float16* __restrict__ q16, _Float16* __restrict__ k16, _Float16* __restrict__ v16) {
  int i = blockIdx.x, tid = threadIdx.x;
  int c = tid * 4;
  const _Float16* rowp = &prebuf[(size_t)i * 4096];
  f16x4 qh = *(const f16x4*)&rowp[c];
  f16x4 kh = *(const f16x4*)&rowp[1024 + c];
  f16x4 vh = *(const f16x4*)&rowp[2048 + c];
  float qv[4], kv[4];
#pragma unroll
  for (int e = 0; e < 4; ++e) { qv[e] = (float)qh[e]; kv[e] = (float)kh[e]; }
  float qs = qv[0] + qv[1] + qv[2] + qv[3];
  float qss = qv[0] * qv[0] + qv[1] * qv[1] + qv[2] * qv[2] + qv[3] * qv[3];
  float ks = kv[0] + kv[1] + kv[2] + kv[3];
  float kss = kv[0] * kv[0] + kv[1] * kv[1] + kv[2] * kv[2] + kv[3] * kv[3];
  qs = wave_sum(qs); qss = wave_sum(qss); ks = wave_sum(ks); kss = wave_sum(kss);
  __shared__ float red[4][4];
  int w = tid >> 6;
  if ((tid & 63) == 0) { red[0][w] = qs; red[1][w] = qss; red[2][w] = ks; red[3][w] = kss; }
  __syncthreads();
  qs = red[0][0] + red[0][1] + red[0][2] + red[0][3];
  qss = red[1][0] + red[1][1] + red[1][2] + red[1][3];
  ks = red[2][0] + red[2][1] + red[2][2] + red[2][3];
  kss = red[3][0] + red[3][1] + red[3][2] + red[3][3];
  float qm = qs * (1.f / INNER), qvr = qss * (1.f / INNER) - qm * qm, qr = rsqrtf(qvr + 1e-5f);
  float km = ks * (1.f / INNER), kvr = kss * (1.f / INNER) - km * km, kr = rsqrtf(kvr + 1e-5f);
  int hh = c >> 6, d = c & 63;
  size_t off = ((size_t)hh * NN + i) * DHD + d;
  f16x4 qo, ko;
#pragma unroll
  for (int e = 0; e < 4; ++e) {
    qo[e] = (_Float16)((qv[e] - qm) * qr * qg[c + e] + qb[c + e]);
    ko[e] = (_Float16)((kv[e] - km) * kr * kg[c + e] + kb[c + e]);
  }
  *(f16x4*)&q16[off] = qo;
  *(f16x4*)&k16[off] = ko;
  *(f16x4*)&v16[off] = vh;
}

// ---------------- flash attention: LDS K/V reg-prefetch, direct bias ----------------
__global__ __launch_bounds__(256) void attn_kernel(const _Float16* __restrict__ q16,
    const _Float16* __restrict__ k16, const _Float16* __restrict__ vT16,
    const _Float16* __restrict__ bias16, _Float16* __restrict__ opart,
    float* __restrict__ mlbuf) {
  int it = blockIdx.x, h = blockIdx.y, ck = blockIdx.z;
  int tid = threadIdx.x, lane = tid & 63, w = tid >> 6;
  int lr = lane & 15, lg = lane >> 4;
  __shared__ _Float16 Kt[64][72];
  __shared__ _Float16 Vt[64][72];
  int ib0 = it * 64;
  int ib = ib0 + w * 16;
  f16x8 qb0 = *(const f16x8*)&q16[((size_t)h * NN + ib + lr) * DHD + lg * 8];
  f16x8 qb1 = *(const f16x8*)&q16[((size_t)h * NN + ib + lr) * DHD + 32 + lg * 8];
  float m = -INFINITY, lsum = 0.f;
  f32x4 oacc[4] = {};
  int sr = tid >> 3, sc = (tid & 7) * 8;
  int jt0g = ck * JT_PER;
  const _Float16* brow = &bias16[((size_t)h * NN + ib + lr) * NN];
  f16x8 kA, kB, vA, vB;
  {
    int j0 = jt0g * 64;
    kA = *(const f16x8*)&k16[((size_t)h * NN + j0 + sr) * DHD + sc];
    kB = *(const f16x8*)&k16[((size_t)h * NN + j0 + sr + 32) * DHD + sc];
    vA = *(const f16x8*)&vT16[((size_t)h * DHD + sr) * NN + j0 + sc];
    vB = *(const f16x8*)&vT16[((size_t)h * DHD + sr + 32) * NN + j0 + sc];
  }
  for (int jj = 0; jj < JT_PER; ++jj) {
    int j0 = (jt0g + jj) * 64;
    *(f16x8*)&Kt[sr][sc] = kA;
    *(f16x8*)&Kt[sr + 32][sc] = kB;
    *(f16x8*)&Vt[sr][sc] = vA;
    *(f16x8*)&Vt[sr + 32][sc] = vB;
    f16x4 bl[4];
#pragma unroll
    for (int jq = 0; jq < 4; ++jq)
      bl[jq] = *(const f16x4*)&brow[j0 + jq * 16 + lg * 4];
    __syncthreads();
    if (jj + 1 < JT_PER) {
      int j1 = j0 + 64;
      kA = *(const f16x8*)&k16[((size_t)h * NN + j1 + sr) * DHD + sc];
      kB = *(const f16x8*)&k16[((size_t)h * NN + j1 + sr + 32) * DHD + sc];
      vA = *(const f16x8*)&vT16[((size_t)h * DHD + sr) * NN + j1 + sc];
      vB = *(const f16x8*)&vT16[((size_t)h * DHD + sr + 32) * NN + j1 + sc];
    }
    float s[4][4];
#pragma unroll
    for (int jq = 0; jq < 4; ++jq) {
      f16x8 ka0 = *(const f16x8*)&Kt[jq * 16 + lr][lg * 8];
      f16x8 ka1 = *(const f16x8*)&Kt[jq * 16 + lr][32 + lg * 8];
      f32x4 c = {};
      c = __builtin_amdgcn_mfma_f32_16x16x32_f16(ka0, qb0, c, 0, 0, 0);
      c = __builtin_amdgcn_mfma_f32_16x16x32_f16(ka1, qb1, c, 0, 0, 0);
#pragma unroll
      for (int r = 0; r < 4; ++r)
        s[jq][r] = c[r] * 0.125f + (float)bl[jq][r];
    }
    float tmax = s[0][0];
#pragma unroll
    for (int jq = 0; jq < 4; ++jq)
#pragma unroll
      for (int r = 0; r < 4; ++r) tmax = fmaxf(tmax, s[jq][r]);
    tmax = fmaxf(tmax, __shfl_xor(tmax, 16));
    tmax = fmaxf(tmax, __shfl_xor(tmax, 32));
    float mn = fmaxf(m, tmax);
    float alpha = __expf(m - mn);
    float ps = 0.f;
    f16x4 pf[4];
#pragma unroll
    for (int jq = 0; jq < 4; ++jq)
#pragma unroll
      for (int r = 0; r < 4; ++r) {
        float p = __expf(s[jq][r] - mn);
        ps += p;
        pf[jq][r] = (_Float16)p;
      }
    ps += __shfl_xor(ps, 16);
    ps += __shfl_xor(ps, 32);
    lsum = lsum * alpha + ps;
    m = mn;
    float ar[4];
#pragma unroll
    for (int r = 0; r < 4; ++r) ar[r] = __shfl(alpha, lg * 4 + r);
#pragma unroll
    for (int dt = 0; dt < 4; ++dt)
#pragma unroll
      for (int r = 0; r < 4; ++r) oacc[dt][r] *= ar[r];
#pragma unroll
    for (int dt = 0; dt < 4; ++dt)
#pragma unroll
      for (int jq = 0; jq < 4; ++jq) {
        f16x4 vb = *(const f16x4*)&Vt[dt * 16 + lr][jq * 16 + lg * 4];
        oacc[dt] = __builtin_amdgcn_mfma_f32_16x16x16f16(pf[jq], vb, oacc[dt], 0, 0, 0);
      }
    __syncthreads();
  }
  size_t pbase = (((size_t)it * HH + h) * NCHUNK + ck) * 4096 + (size_t)w * 1024;
#pragma unroll
  for (int dt = 0; dt < 4; ++dt) {
    f16x4 ov;
#pragma unroll
    for (int r = 0; r < 4; ++r) ov[r] = (_Float16)oacc[dt][r];
    *(f16x4*)&opart[pbase + dt * 256 + lane * 4] = ov;
  }
  if (lg == 0) {
    size_t mb = (((size_t)it * HH + h) * NCHUNK + ck) * 128;
    mlbuf[mb + w * 16 + lr] = m;
    mlbuf[mb + 64 + w * 16 + lr] = lsum;
  }
}

// ---------------- flash merge + gating -> o16 ----------------
__global__ __launch_bounds__(256) void attn_merge(const _Float16* __restrict__ opart,
    const float* __restrict__ mlbuf, const _Float16* __restrict__ prebuf,
    _Float16* __restrict__ o16) {
  int it = blockIdx.x, h = blockIdx.y;
  int tid = threadIdx.x, lane = tid & 63, w = tid >> 6;
  int lr = lane & 15, lg = lane >> 4;
  __shared__ float sm[NCHUNK][64], sl[NCHUNK][64];
  {
    int c = tid >> 6, i = tid & 63;
    size_t mb = (((size_t)it * HH + h) * NCHUNK + c) * 128;
    sm[c][i] = mlbuf[mb + i];
    sl[c][i] = mlbuf[mb + 64 + i];
  }
  __syncthreads();
  float wc[NCHUNK][4], linv[4];
#pragma unroll
  for (int r = 0; r < 4; ++r) {
    int i_loc = w * 16 + lg * 4 + r;
    float mg = sm[0][i_loc];
#pragma unroll
    for (int c = 1; c < NCHUNK; ++c) mg = fmaxf(mg, sm[c][i_loc]);
    float lt = 0.f;
#pragma unroll
    for (int c = 0; c < NCHUNK; ++c) {
      float e = __expf(sm[c][i_loc] - mg);
      wc[c][r] = e;
      lt += e * sl[c][i_loc];
    }
    linv[r] = 1.f / lt;
  }
  size_t base = ((size_t)it * HH + h) * NCHUNK * 4096 + (size_t)w * 1024;
#pragma unroll
  for (int dt = 0; dt < 4; ++dt) {
    float o[4] = {};
#pragma unroll
    for (int c = 0; c < NCHUNK; ++c) {
      f16x4 v = *(const f16x4*)&opart[base + (size_t)c * 4096 + dt * 256 + lane * 4];
#pragma unroll
      for (int r = 0; r < 4; ++r) o[r] += wc[c][r] * (float)v[r];
    }
    int d = dt * 16 + lr;
#pragma unroll
    for (int r = 0; r < 4; ++r) {
      int i = it * 64 + w * 16 + lg * 4 + r;
      float gt = (float)prebuf[(size_t)i * 4096 + 3072 + h * DHD + d];
      float val = o[r] * linv[r] * (1.f / (1.f + __expf(-gt)));
      o16[(size_t)i * INNER + h * DHD + d] = (_Float16)val;
    }
  }
}

extern "C" void kernel_launch(void* const* d_in, const int* in_sizes, int n_in,
                              void* d_out, int out_size, void* d_ws, size_t ws_size,
                              hipStream_t stream) {
  const float* node  = (const float*)d_in[0];
  const float* pair  = (const float*)d_in[1];
  const float* ln_ng = (const float*)d_in[3];
  const float* ln_nb = (const float*)d_in[4];
  const float* ln_pg = (const float*)d_in[5];
  const float* ln_pb = (const float*)d_in[6];
  const float* Wq    = (const float*)d_in[7];
  const float* bq    = (const float*)d_in[8];
  const float* Wkv   = (const float*)d_in[9];
  const float* bkv   = (const float*)d_in[10];
  const float* qlg   = (const float*)d_in[11];
  const float* qlb   = (const float*)d_in[12];
  const float* klg   = (const float*)d_in[13];
  const float* klb   = (const float*)d_in[14];
  const float* Wg    = (const float*)d_in[15];
  const float* bg    = (const float*)d_in[16];
  const float* Wbias = (const float*)d_in[17];
  const float* Wout  = (const float*)d_in[18];
  const float* bout  = (const float*)d_in[19];
  float* out = (float*)d_out;

  char* ws = (char*)d_ws;
  const size_t MB = 1u << 20;
  _Float16* BTall    = (_Float16*)(ws + 0 * MB);
  _Float16* WoutT    = (_Float16*)(ws + 4 * MB);
  _Float16* x16      = (_Float16*)(ws + 5 * MB);
  _Float16* prebuf16 = (_Float16*)(ws + 8 * MB);
  _Float16* q16      = (_Float16*)(ws + 20 * MB);
  _Float16* k16      = (_Float16*)(ws + 23 * MB);
  _Float16* v16      = (_Float16*)(ws + 26 * MB);
  _Float16* vT16     = (_Float16*)(ws + 29 * MB);
  _Float16* o16      = (_Float16*)(ws + 32 * MB);
  _Float16* bias16   = (_Float16*)(ws + 36 * MB);
  _Float16* opart    = (_Float16*)(ws + 112 * MB);
  float*    mlbuf    = (float*)(ws + 126 * MB);

  prep_kernel<<<640 + NN, 256, 0, stream>>>(Wq, Wkv, Wg, Wout, node, ln_ng, ln_nb,
                                            BTall, WoutT, x16);
  // fat: pair_bias (9216) + gemm_proj (1536) interleaved 6:1
  fat_pb_gemm<<<10752, 256, 0, stream>>>(pair, ln_pg, ln_pb, Wbias, bias16,
                                         x16, BTall, bq, bkv, bg, prebuf16);
  qkv_ln_kernel<<<NN, 256, 0, stream>>>(prebuf16, qlg, qlb, klg, klb, q16, k16, v16);
  transpose_f16_b<<<dim3(1, NN / 64, HH), 256, 0, stream>>>(v16, vT16, NN, DHD);
  attn_kernel<<<dim3(NN / 64, HH, NCHUNK), 256, 0, stream>>>(q16, k16, vT16, bias16, opart, mlbuf);
  attn_merge<<<dim3(NN / 64, HH), 256, 0, stream>>>(opart, mlbuf, prebuf16, o16);
  gemm_f16<<<dim3(DD / 64, NN / 64), 256, 0, stream>>>(o16, WoutT, bout, out, NN, DD, INNER);
}